// Round 1
// baseline (591.331 us; speedup 1.0000x reference)
//
#include <hip/hip_runtime.h>
#include <hip/hip_bf16.h>

// BatchSplitFF: DM=1024, NEXPERTS=32, SETS=4 (ES=128 pairs), ESIZE=32, B=2, S=8192
// groups: 512 total, 32 tokens each. es = e*4+s everywhere (matches all input layouts).
#define DM   1024
#define NES  128
#define GT   32
#define NGRP 512
#define FSZ  32

// ---------------------------------------------------------------------------
// Kernel A: controller logits (f32, tree-accumulated) + argmax-equality mask.
// One block per group. C(32t x 128es) = X(32x1024) . Wc(1024x128), K-chunked.
// ---------------------------------------------------------------------------
__global__ __launch_bounds__(256, 2) void kA(const float* __restrict__ x,
                                             const float* __restrict__ Wc,
                                             const float* __restrict__ bc,
                                             unsigned int* __restrict__ sel) {
  __shared__ float wcs[64 * 128];   // Wc chunk [dd][es]    32 KB
  __shared__ float xs[32 * 64];     // x  chunk [t][dd]      8 KB
  __shared__ float lg[32 * 128];    // logits  [t][es]      16 KB
  const int g   = blockIdx.x;
  const int tid = threadIdx.x;
  const int es0 = (tid & 31) * 4;   // 4 es per thread (contiguous -> float4)
  const int t0  = (tid >> 5) * 4;   // 4 t per thread
  const float* xg = x + (size_t)g * GT * DM;

  float acc[16];
#pragma unroll
  for (int i = 0; i < 16; ++i) acc[i] = 0.f;

  for (int c = 0; c < 16; ++c) {
    const int d0 = c * 64;
    if (c) __syncthreads();
#pragma unroll
    for (int k = 0; k < 8; ++k) {   // stage Wc chunk (8192 f32)
      int idx = (tid + 256 * k) * 4;
      int dd = idx >> 7, es = idx & 127;
      *(float4*)&wcs[idx] = *(const float4*)&Wc[(size_t)(d0 + dd) * NES + es];
    }
#pragma unroll
    for (int k = 0; k < 2; ++k) {   // stage x chunk (2048 f32)
      int idx = (tid + 256 * k) * 4;
      int t = idx >> 6, dd = idx & 63;
      *(float4*)&xs[idx] = *(const float4*)&xg[(size_t)t * DM + d0 + dd];
    }
    __syncthreads();

    float part[16];                 // per-chunk partials (tree accumulation:
#pragma unroll                      // keeps rounding noise ~4x below 1024-chain)
    for (int i = 0; i < 16; ++i) part[i] = 0.f;
    for (int dd = 0; dd < 64; ++dd) {
      float4 wv = *(const float4*)&wcs[dd * NES + es0];   // stride-1 banks
      float xv0 = xs[(t0 + 0) * 64 + dd];                 // broadcast reads
      float xv1 = xs[(t0 + 1) * 64 + dd];
      float xv2 = xs[(t0 + 2) * 64 + dd];
      float xv3 = xs[(t0 + 3) * 64 + dd];
      part[0]  += xv0 * wv.x; part[1]  += xv0 * wv.y; part[2]  += xv0 * wv.z; part[3]  += xv0 * wv.w;
      part[4]  += xv1 * wv.x; part[5]  += xv1 * wv.y; part[6]  += xv1 * wv.z; part[7]  += xv1 * wv.w;
      part[8]  += xv2 * wv.x; part[9]  += xv2 * wv.y; part[10] += xv2 * wv.z; part[11] += xv2 * wv.w;
      part[12] += xv3 * wv.x; part[13] += xv3 * wv.y; part[14] += xv3 * wv.z; part[15] += xv3 * wv.w;
    }
#pragma unroll
    for (int i = 0; i < 16; ++i) acc[i] += part[i];
  }
  __syncthreads();

  // logits = (dot + bc) + tie, same op order as reference
#pragma unroll
  for (int i = 0; i < 4; ++i) {
    int t = t0 + i;
    float tie = (float)((double)t * (1e-6 / 31.0));
#pragma unroll
    for (int j = 0; j < 4; ++j) {
      int es = es0 + j;
      lg[t * NES + es] = (acc[i * 4 + j] + bc[es]) + tie;
    }
  }
  __syncthreads();
  if (tid < NES) {   // per-es: max over 32 tokens, equality bitmask (ties kept)
    float m = -INFINITY;
    for (int t = 0; t < GT; ++t) m = fmaxf(m, lg[t * NES + tid]);
    unsigned int msk = 0u;
    for (int t = 0; t < GT; ++t) if (lg[t * NES + tid] == m) msk |= (1u << t);
    sel[(size_t)g * NES + tid] = msk;
  }
}

// ---------------------------------------------------------------------------
// Kernel B: inner = relu(xsel . W1[es] + b1[es]).  Block = (es, 32-group chunk).
// W1 amortized over 32 groups per block; acc in registers (f,4g per thread).
// ---------------------------------------------------------------------------
__global__ __launch_bounds__(256, 2) void kB(const float* __restrict__ x,
                                             const float* __restrict__ W1,
                                             const float* __restrict__ b1,
                                             const unsigned int* __restrict__ sel,
                                             float* __restrict__ inner) {
  __shared__ float w1s[256 * FSZ];          // W1 chunk [dd][f]  32 KB
  __shared__ float xss[32 * 256];           // xsel     [g][dd]  32 KB
  __shared__ unsigned int msks[32];
  const int bid = blockIdx.x;
  const int es  = bid >> 4;                 // adjacent blocks share es -> W1 L2 reuse
  const int g0  = (bid & 15) * 32;
  const int tid = threadIdx.x;
  const int f   = tid & 31;
  const int gp  = tid >> 5;                 // thread's groups: gp, gp+8, gp+16, gp+24
  if (tid < 32) msks[tid] = sel[(size_t)(g0 + tid) * NES + es];

  float acc[4] = {0.f, 0.f, 0.f, 0.f};
  for (int c = 0; c < 4; ++c) {
    const int d0 = c * 256;
    __syncthreads();                        // also covers msks on c==0
    const float* w1p = W1 + (size_t)es * DM * FSZ + (size_t)d0 * FSZ;
#pragma unroll
    for (int k = 0; k < 8; ++k) {           // stage W1 chunk (8192 f32), straight copy
      int idx = (tid + 256 * k) * 4;
      *(float4*)&w1s[idx] = *(const float4*)&w1p[idx];
    }
    {                                       // stage selected rows (8 loaders per row)
      int r = tid >> 3, p = tid & 7;
      unsigned int m = msks[r];
      size_t grow = (size_t)(g0 + r) * GT;
      if (m & (m - 1)) {                    // rare multi-tie: dispatch the SUM
        for (int j = 0; j < 32; ++j) {
          float v = 0.f; unsigned int mm = m;
          while (mm) { int tt = __ffs(mm) - 1; mm &= mm - 1;
            v += x[(grow + tt) * DM + d0 + p * 32 + j]; }
          xss[r * 256 + p * 32 + j] = v;
        }
      } else {
        int t = __ffs(m) - 1;
        const float4* xr = (const float4*)(x + (grow + t) * DM + d0 + p * 32);
        float4* dst = (float4*)&xss[r * 256 + p * 32];
#pragma unroll
        for (int j = 0; j < 8; ++j) dst[j] = xr[j];
      }
    }
    __syncthreads();
    for (int dd = 0; dd < 256; dd += 4) {
      float wv0 = w1s[(dd + 0) * FSZ + f];  // stride-1 banks
      float wv1 = w1s[(dd + 1) * FSZ + f];
      float wv2 = w1s[(dd + 2) * FSZ + f];
      float wv3 = w1s[(dd + 3) * FSZ + f];
#pragma unroll
      for (int i = 0; i < 4; ++i) {
        float4 xv = *(const float4*)&xss[(gp + i * 8) * 256 + dd];  // broadcast
        acc[i] += fmaf(xv.x, wv0, fmaf(xv.y, wv1, fmaf(xv.z, wv2, xv.w * wv3)));
      }
    }
  }
  float b1v = b1[es * FSZ + f];
#pragma unroll
  for (int i = 0; i < 4; ++i) {
    int g = g0 + gp + i * 8;
    inner[((size_t)g * NES + es) * FSZ + f] = fmaxf(acc[i] + b1v, 0.f);
  }
}

// ---------------------------------------------------------------------------
// Kernel C: out += scatter_t( inner . W2[es]^T + b2[es] ), summed over es.
// Block = (32-group chunk, 32-d chunk); output tile accumulated in LDS
// (exclusive ownership -> no atomics). Thread owns unique (g,dd) per es.
// ---------------------------------------------------------------------------
__global__ __launch_bounds__(256, 1) void kC(const float* __restrict__ W2,
                                             const float* __restrict__ b2,
                                             const unsigned int* __restrict__ sel,
                                             const float* __restrict__ inner,
                                             float* __restrict__ out) {
  __shared__ float outs[32 * 32 * 32];      // [g][t][dd] accumulator, 128 KB
  __shared__ float inns[32 * 36];           // [g][f] pad36 (16B-aligned rows)
  __shared__ float w2s[32 * 36];            // [dd][f] pad36
  __shared__ unsigned int msk2[32];
  const int bid = blockIdx.x;
  const int d0  = (bid & 31) * 32;
  const int g0  = (bid >> 5) * 32;
  const int tid = threadIdx.x;
  const int dd  = tid & 31;
  const int gp  = tid >> 5;                 // groups gp, gp+8, gp+16, gp+24
#pragma unroll
  for (int k = 0; k < 32; ++k)              // zero the tile (covers unselected tokens)
    *(float4*)&outs[(tid + 256 * k) * 4] = make_float4(0.f, 0.f, 0.f, 0.f);

  for (int es = 0; es < NES; ++es) {
    __syncthreads();
    if (tid < 32) msk2[tid] = sel[(size_t)(g0 + tid) * NES + es];
    {
      int gg = tid >> 3, q = (tid & 7) * 4;
      *(float4*)&inns[gg * 36 + q] =
          *(const float4*)&inner[((size_t)(g0 + gg) * NES + es) * FSZ + q];
      *(float4*)&w2s[gg * 36 + q] =
          *(const float4*)&W2[(size_t)es * DM * FSZ + (size_t)(d0 + gg) * FSZ + q];
    }
    __syncthreads();
    float accA[4] = {0.f, 0.f, 0.f, 0.f};   // split chains for ILP
    float accB[4] = {0.f, 0.f, 0.f, 0.f};
    for (int fp = 0; fp < FSZ; fp += 2) {
      float2 wv = *(const float2*)&w2s[dd * 36 + fp];
#pragma unroll
      for (int i = 0; i < 4; ++i) {
        float2 iv = *(const float2*)&inns[(gp + i * 8) * 36 + fp];  // broadcast
        accA[i] += iv.x * wv.x;
        accB[i] += iv.y * wv.y;
      }
    }
    float b2v = b2[(size_t)es * DM + d0 + dd];
#pragma unroll
    for (int i = 0; i < 4; ++i) {
      int g = gp + i * 8;
      unsigned int m = msk2[g];
      float val = accA[i] + accB[i] + b2v;  // b2 once per (es) selection
      while (m) { int t = __ffs(m) - 1; m &= m - 1;   // scatter to all tied tokens
        outs[(g * GT + t) * 32 + dd] += val; }        // unique (g,dd) -> race-free
    }
  }
  __syncthreads();
#pragma unroll
  for (int k = 0; k < 32; ++k) {
    int idx = (tid + 256 * k) * 4;
    int g = idx >> 10, t = (idx >> 5) & 31, d2 = idx & 31;
    *(float4*)&out[((size_t)(g0 + g) * GT + t) * DM + d0 + d2] =
        *(const float4*)&outs[idx];
  }
}

extern "C" void kernel_launch(void* const* d_in, const int* in_sizes, int n_in,
                              void* d_out, int out_size, void* d_ws, size_t ws_size,
                              hipStream_t stream) {
  const float* x  = (const float*)d_in[0];
  const float* Wc = (const float*)d_in[1];
  const float* bc = (const float*)d_in[2];
  const float* W1 = (const float*)d_in[3];
  const float* b1 = (const float*)d_in[4];
  const float* W2 = (const float*)d_in[5];
  const float* b2 = (const float*)d_in[6];
  float* out = (float*)d_out;

  // ws: sel masks u32[512*128] at 0 (256 KB); inner f32[512*128*32] at 1 MB (8 MB).
  unsigned int* sel = (unsigned int*)d_ws;
  float* inner = (float*)((char*)d_ws + (1 << 20));

  kA<<<NGRP, 256, 0, stream>>>(x, Wc, bc, sel);
  kB<<<NES * 16, 256, 0, stream>>>(x, W1, b1, sel, inner);
  kC<<<NGRP, 256, 0, stream>>>(W2, b2, sel, inner, out);
}

// Round 2
// 585.440 us; speedup vs baseline: 1.0101x; 1.0101x over previous
//
#include <hip/hip_runtime.h>
#include <hip/hip_bf16.h>

// BatchSplitFF: DM=1024, NEXPERTS=32, SETS=4 (ES=128 pairs), ESIZE=32, B=2, S=8192
#define DM   1024
#define NES  128
#define GT   32
#define NGRP 512
#define FSZ  32

typedef float f32x4 __attribute__((ext_vector_type(4)));
typedef short s16x8 __attribute__((ext_vector_type(8)));

__device__ inline unsigned short f2bf(float f) {   // RNE f32->bf16
  union { float f; unsigned int u; } x; x.f = f;
  unsigned int r = x.u + 0x7fffu + ((x.u >> 16) & 1u);
  return (unsigned short)(r >> 16);
}

// ---------------------------------------------------------------------------
// Kernel A: controller logits (f32, tree-accumulated) + argmax-equality mask.
// UNCHANGED from round 1 (passed; argmax is rounding-sensitive, stays f32).
// ---------------------------------------------------------------------------
__global__ __launch_bounds__(256, 2) void kA(const float* __restrict__ x,
                                             const float* __restrict__ Wc,
                                             const float* __restrict__ bc,
                                             unsigned int* __restrict__ sel) {
  __shared__ float wcs[64 * 128];
  __shared__ float xs[32 * 64];
  __shared__ float lg[32 * 128];
  const int g   = blockIdx.x;
  const int tid = threadIdx.x;
  const int es0 = (tid & 31) * 4;
  const int t0  = (tid >> 5) * 4;
  const float* xg = x + (size_t)g * GT * DM;

  float acc[16];
#pragma unroll
  for (int i = 0; i < 16; ++i) acc[i] = 0.f;

  for (int c = 0; c < 16; ++c) {
    const int d0 = c * 64;
    if (c) __syncthreads();
#pragma unroll
    for (int k = 0; k < 8; ++k) {
      int idx = (tid + 256 * k) * 4;
      int dd = idx >> 7, es = idx & 127;
      *(float4*)&wcs[idx] = *(const float4*)&Wc[(size_t)(d0 + dd) * NES + es];
    }
#pragma unroll
    for (int k = 0; k < 2; ++k) {
      int idx = (tid + 256 * k) * 4;
      int t = idx >> 6, dd = idx & 63;
      *(float4*)&xs[idx] = *(const float4*)&xg[(size_t)t * DM + d0 + dd];
    }
    __syncthreads();

    float part[16];
#pragma unroll
    for (int i = 0; i < 16; ++i) part[i] = 0.f;
    for (int dd = 0; dd < 64; ++dd) {
      float4 wv = *(const float4*)&wcs[dd * NES + es0];
      float xv0 = xs[(t0 + 0) * 64 + dd];
      float xv1 = xs[(t0 + 1) * 64 + dd];
      float xv2 = xs[(t0 + 2) * 64 + dd];
      float xv3 = xs[(t0 + 3) * 64 + dd];
      part[0]  += xv0 * wv.x; part[1]  += xv0 * wv.y; part[2]  += xv0 * wv.z; part[3]  += xv0 * wv.w;
      part[4]  += xv1 * wv.x; part[5]  += xv1 * wv.y; part[6]  += xv1 * wv.z; part[7]  += xv1 * wv.w;
      part[8]  += xv2 * wv.x; part[9]  += xv2 * wv.y; part[10] += xv2 * wv.z; part[11] += xv2 * wv.w;
      part[12] += xv3 * wv.x; part[13] += xv3 * wv.y; part[14] += xv3 * wv.z; part[15] += xv3 * wv.w;
    }
#pragma unroll
    for (int i = 0; i < 16; ++i) acc[i] += part[i];
  }
  __syncthreads();

#pragma unroll
  for (int i = 0; i < 4; ++i) {
    int t = t0 + i;
    float tie = (float)((double)t * (1e-6 / 31.0));
#pragma unroll
    for (int j = 0; j < 4; ++j) {
      int es = es0 + j;
      lg[t * NES + es] = (acc[i * 4 + j] + bc[es]) + tie;
    }
  }
  __syncthreads();
  if (tid < NES) {
    float m = -INFINITY;
    for (int t = 0; t < GT; ++t) m = fmaxf(m, lg[t * NES + tid]);
    unsigned int msk = 0u;
    for (int t = 0; t < GT; ++t) if (lg[t * NES + tid] == m) msk |= (1u << t);
    sel[(size_t)g * NES + tid] = msk;
  }
}

// ---------------------------------------------------------------------------
// kW2: repack W2 f32 [es][d][f] -> bf16 MFMA-B fragment order.
// Element (es, dt, lane, i) = B[k=(lane>>4)*8+i][col=lane&15] of the 16x16x32
// tile at d-tile dt, i.e. W2[es][dt*16+(lane&15)][(lane>>4)*8+i].
// ---------------------------------------------------------------------------
__global__ __launch_bounds__(256) void kW2(const float* __restrict__ W2,
                                           unsigned short* __restrict__ W2f) {
  int idx = blockIdx.x * 256 + threadIdx.x;      // (es, dt, lane)
  int l = idx & 63, dt = (idx >> 6) & 63, es = idx >> 12;
  const float* src = W2 + ((size_t)es * DM + dt * 16 + (l & 15)) * FSZ + (l >> 4) * 8;
  float4 a = *(const float4*)src;
  float4 b = *(const float4*)(src + 4);
  s16x8 v;
  v[0] = (short)f2bf(a.x); v[1] = (short)f2bf(a.y);
  v[2] = (short)f2bf(a.z); v[3] = (short)f2bf(a.w);
  v[4] = (short)f2bf(b.x); v[5] = (short)f2bf(b.y);
  v[6] = (short)f2bf(b.z); v[7] = (short)f2bf(b.w);
  *(s16x8*)(W2f + (size_t)idx * 8) = v;
}

// ---------------------------------------------------------------------------
// Kernel B: inner = relu(xsel . W1[es] + b1[es]) -> bf16 [g][es][f].
// f32 compute unchanged from round 1; only the store dtype changed.
// ---------------------------------------------------------------------------
__global__ __launch_bounds__(256, 2) void kB(const float* __restrict__ x,
                                             const float* __restrict__ W1,
                                             const float* __restrict__ b1,
                                             const unsigned int* __restrict__ sel,
                                             unsigned short* __restrict__ innerb) {
  __shared__ float w1s[256 * FSZ];
  __shared__ float xss[32 * 256];
  __shared__ unsigned int msks[32];
  const int bid = blockIdx.x;
  const int es  = bid >> 4;
  const int g0  = (bid & 15) * 32;
  const int tid = threadIdx.x;
  const int f   = tid & 31;
  const int gp  = tid >> 5;
  if (tid < 32) msks[tid] = sel[(size_t)(g0 + tid) * NES + es];

  float acc[4] = {0.f, 0.f, 0.f, 0.f};
  for (int c = 0; c < 4; ++c) {
    const int d0 = c * 256;
    __syncthreads();
    const float* w1p = W1 + (size_t)es * DM * FSZ + (size_t)d0 * FSZ;
#pragma unroll
    for (int k = 0; k < 8; ++k) {
      int idx = (tid + 256 * k) * 4;
      *(float4*)&w1s[idx] = *(const float4*)&w1p[idx];
    }
    {
      int r = tid >> 3, p = tid & 7;
      unsigned int m = msks[r];
      size_t grow = (size_t)(g0 + r) * GT;
      if (m & (m - 1)) {                    // rare multi-tie: dispatch the SUM
        for (int j = 0; j < 32; ++j) {
          float v = 0.f; unsigned int mm = m;
          while (mm) { int tt = __ffs(mm) - 1; mm &= mm - 1;
            v += x[(grow + tt) * DM + d0 + p * 32 + j]; }
          xss[r * 256 + p * 32 + j] = v;
        }
      } else {
        int t = __ffs(m) - 1;
        const float4* xr = (const float4*)(x + (grow + t) * DM + d0 + p * 32);
        float4* dst = (float4*)&xss[r * 256 + p * 32];
#pragma unroll
        for (int j = 0; j < 8; ++j) dst[j] = xr[j];
      }
    }
    __syncthreads();
    for (int dd = 0; dd < 256; dd += 4) {
      float wv0 = w1s[(dd + 0) * FSZ + f];
      float wv1 = w1s[(dd + 1) * FSZ + f];
      float wv2 = w1s[(dd + 2) * FSZ + f];
      float wv3 = w1s[(dd + 3) * FSZ + f];
#pragma unroll
      for (int i = 0; i < 4; ++i) {
        float4 xv = *(const float4*)&xss[(gp + i * 8) * 256 + dd];
        acc[i] += fmaf(xv.x, wv0, fmaf(xv.y, wv1, fmaf(xv.z, wv2, xv.w * wv3)));
      }
    }
  }
  float b1v = b1[es * FSZ + f];
#pragma unroll
  for (int i = 0; i < 4; ++i) {
    int g = g0 + gp + i * 8;
    innerb[((size_t)g * NES + es) * FSZ + f] = f2bf(fmaxf(acc[i] + b1v, 0.f));
  }
}

// ---------------------------------------------------------------------------
// Kernel C (MFMA rewrite): out += scatter_t( inner . W2[es]^T + b2[es] ).
// Block = 32 groups x 32 d. 4 waves, each owns its own es-stream (es=it*4+w):
// A/B frags straight from global (1-deep reg prefetch), 4x mfma 16x16x32,
// scatter via LDS atomicAdd into shared outs tile. NO barriers in main loop.
// ---------------------------------------------------------------------------
__global__ __launch_bounds__(256, 1) void kC(const unsigned short* __restrict__ innerb,
                                             const unsigned short* __restrict__ W2f,
                                             const float* __restrict__ b2,
                                             const unsigned int* __restrict__ sel,
                                             float* __restrict__ out) {
  __shared__ float outs[32 * 32 * 32];        // [g][t][dd^swz]  128 KB
  __shared__ unsigned int msk[32 * 129];      // [g][es], row-pad 129 (bank spread)
  const int bid = blockIdx.x;
  const int d0  = (bid & 31) * 32;            // d-block fastest -> XCD spread
  const int g0  = (bid >> 5) * 32;
  const int tid = threadIdx.x;
  const int l   = tid & 63, w = tid >> 6;
  const int r15 = l & 15, q = l >> 4;         // frag row/col + k-quad

#pragma unroll
  for (int k = 0; k < 16; ++k) {              // stage masks [32][128] -> pad 129
    int i = tid + 256 * k;
    msk[(i >> 7) * 129 + (i & 127)] = sel[(size_t)(g0 + (i >> 7)) * NES + (i & 127)];
  }
#pragma unroll
  for (int k = 0; k < 32; ++k)                // zero accumulator tile
    *(float4*)&outs[(tid + 256 * k) * 4] = make_float4(0.f, 0.f, 0.f, 0.f);
  __syncthreads();

  const unsigned short* Abase = innerb + (size_t)q * 8;
  const unsigned short* Bbase = W2f + ((size_t)(d0 >> 4) * 64 + l) * 8;

  int es = w;
  s16x8 a0 = *(const s16x8*)(Abase + ((size_t)(g0 + r15) * NES + es) * FSZ);
  s16x8 a1 = *(const s16x8*)(Abase + ((size_t)(g0 + 16 + r15) * NES + es) * FSZ);
  s16x8 b0 = *(const s16x8*)(Bbase + (size_t)es * 64 * 64 * 8);
  s16x8 b1 = *(const s16x8*)(Bbase + ((size_t)es * 64 + 1) * 64 * 8);
  float c0 = b2[(size_t)es * DM + d0 + r15];
  float c1 = b2[(size_t)es * DM + d0 + 16 + r15];

  for (int it = 0; it < 32; ++it) {
    const int esn = (it < 31) ? es + 4 : es;  // clamped prefetch (last iter dummy)
    s16x8 na0 = *(const s16x8*)(Abase + ((size_t)(g0 + r15) * NES + esn) * FSZ);
    s16x8 na1 = *(const s16x8*)(Abase + ((size_t)(g0 + 16 + r15) * NES + esn) * FSZ);
    s16x8 nb0 = *(const s16x8*)(Bbase + (size_t)esn * 64 * 64 * 8);
    s16x8 nb1 = *(const s16x8*)(Bbase + ((size_t)esn * 64 + 1) * 64 * 8);
    float nc0 = b2[(size_t)esn * DM + d0 + r15];
    float nc1 = b2[(size_t)esn * DM + d0 + 16 + r15];

    const f32x4 z = {0.f, 0.f, 0.f, 0.f};
    f32x4 acc00 = __builtin_amdgcn_mfma_f32_16x16x32_bf16(a0, b0, z, 0, 0, 0);
    f32x4 acc01 = __builtin_amdgcn_mfma_f32_16x16x32_bf16(a0, b1, z, 0, 0, 0);
    f32x4 acc10 = __builtin_amdgcn_mfma_f32_16x16x32_bf16(a1, b0, z, 0, 0, 0);
    f32x4 acc11 = __builtin_amdgcn_mfma_f32_16x16x32_bf16(a1, b1, z, 0, 0, 0);

#pragma unroll
    for (int gi = 0; gi < 2; ++gi) {
#pragma unroll
      for (int r = 0; r < 4; ++r) {
        const int gl = gi * 16 + q * 4 + r;   // C/D: row=(lane>>4)*4+reg
        unsigned int m = msk[gl * 129 + es];
        const int sw = (gl & 1) << 4;         // 1-bit bank swizzle
        const float v0 = (gi ? acc10[r] : acc00[r]) + c0;
        const float v1 = (gi ? acc11[r] : acc01[r]) + c1;
        while (m) {                            // ties: all selected tokens
          int t = __ffs(m) - 1; m &= m - 1;
          atomicAdd(&outs[gl * 1024 + t * 32 + (r15 ^ sw)], v0);
          atomicAdd(&outs[gl * 1024 + t * 32 + ((r15 + 16) ^ sw)], v1);
        }
      }
    }
    a0 = na0; a1 = na1; b0 = nb0; b1 = nb1; c0 = nc0; c1 = nc1; es = esn;
  }
  __syncthreads();

#pragma unroll
  for (int k = 0; k < 32; ++k) {              // write tile (swizzle-corrected)
    int idx = (tid + 256 * k) * 4;
    int g = idx >> 10, t = (idx >> 5) & 31, d2 = idx & 31;
    int sw = (g & 1) << 4;
    *(float4*)&out[((size_t)(g0 + g) * GT + t) * DM + d0 + (d2 ^ sw)] =
        *(const float4*)&outs[idx];
  }
}

extern "C" void kernel_launch(void* const* d_in, const int* in_sizes, int n_in,
                              void* d_out, int out_size, void* d_ws, size_t ws_size,
                              hipStream_t stream) {
  const float* x  = (const float*)d_in[0];
  const float* Wc = (const float*)d_in[1];
  const float* bc = (const float*)d_in[2];
  const float* W1 = (const float*)d_in[3];
  const float* b1 = (const float*)d_in[4];
  const float* W2 = (const float*)d_in[5];
  const float* b2 = (const float*)d_in[6];
  float* out = (float*)d_out;

  // ws: sel u32[512*128] @0 (256 KB); inner bf16 [g][es][f] @1 MB (4 MB);
  //     W2 bf16 frag-order @6 MB (8.4 MB). Total ~14.4 MB.
  unsigned int* sel = (unsigned int*)d_ws;
  unsigned short* innerb = (unsigned short*)((char*)d_ws + (1 << 20));
  unsigned short* W2f = (unsigned short*)((char*)d_ws + (6u << 20));

  kA<<<NGRP, 256, 0, stream>>>(x, Wc, bc, sel);
  kW2<<<2048, 256, 0, stream>>>(W2, W2f);
  kB<<<NES * 16, 256, 0, stream>>>(x, W1, b1, sel, innerb);
  kC<<<NGRP, 256, 0, stream>>>(innerb, W2f, b2, sel, out);
}

// Round 3
// 384.000 us; speedup vs baseline: 1.5399x; 1.5246x over previous
//
#include <hip/hip_runtime.h>
#include <hip/hip_bf16.h>

// BatchSplitFF: DM=1024, NEXPERTS=32, SETS=4 (ES=128 pairs), ESIZE=32, B=2, S=8192
#define DM   1024
#define NES  128
#define GT   32
#define NGRP 512
#define FSZ  32

typedef float f32x4 __attribute__((ext_vector_type(4)));
typedef short s16x8 __attribute__((ext_vector_type(8)));

__device__ inline unsigned short f2bf(float f) {   // RNE f32->bf16
  union { float f; unsigned int u; } x; x.f = f;
  unsigned int r = x.u + 0x7fffu + ((x.u >> 16) & 1u);
  return (unsigned short)(r >> 16);
}

// ---------------------------------------------------------------------------
// Kernel A: controller logits (f32, tree-accumulated) + argmax-equality mask.
// UNCHANGED (passed twice; argmax is rounding-sensitive, stays f32).
// ---------------------------------------------------------------------------
__global__ __launch_bounds__(256, 2) void kA(const float* __restrict__ x,
                                             const float* __restrict__ Wc,
                                             const float* __restrict__ bc,
                                             unsigned int* __restrict__ sel) {
  __shared__ float wcs[64 * 128];
  __shared__ float xs[32 * 64];
  __shared__ float lg[32 * 128];
  const int g   = blockIdx.x;
  const int tid = threadIdx.x;
  const int es0 = (tid & 31) * 4;
  const int t0  = (tid >> 5) * 4;
  const float* xg = x + (size_t)g * GT * DM;

  float acc[16];
#pragma unroll
  for (int i = 0; i < 16; ++i) acc[i] = 0.f;

  for (int c = 0; c < 16; ++c) {
    const int d0 = c * 64;
    if (c) __syncthreads();
#pragma unroll
    for (int k = 0; k < 8; ++k) {
      int idx = (tid + 256 * k) * 4;
      int dd = idx >> 7, es = idx & 127;
      *(float4*)&wcs[idx] = *(const float4*)&Wc[(size_t)(d0 + dd) * NES + es];
    }
#pragma unroll
    for (int k = 0; k < 2; ++k) {
      int idx = (tid + 256 * k) * 4;
      int t = idx >> 6, dd = idx & 63;
      *(float4*)&xs[idx] = *(const float4*)&xg[(size_t)t * DM + d0 + dd];
    }
    __syncthreads();

    float part[16];
#pragma unroll
    for (int i = 0; i < 16; ++i) part[i] = 0.f;
    for (int dd = 0; dd < 64; ++dd) {
      float4 wv = *(const float4*)&wcs[dd * NES + es0];
      float xv0 = xs[(t0 + 0) * 64 + dd];
      float xv1 = xs[(t0 + 1) * 64 + dd];
      float xv2 = xs[(t0 + 2) * 64 + dd];
      float xv3 = xs[(t0 + 3) * 64 + dd];
      part[0]  += xv0 * wv.x; part[1]  += xv0 * wv.y; part[2]  += xv0 * wv.z; part[3]  += xv0 * wv.w;
      part[4]  += xv1 * wv.x; part[5]  += xv1 * wv.y; part[6]  += xv1 * wv.z; part[7]  += xv1 * wv.w;
      part[8]  += xv2 * wv.x; part[9]  += xv2 * wv.y; part[10] += xv2 * wv.z; part[11] += xv2 * wv.w;
      part[12] += xv3 * wv.x; part[13] += xv3 * wv.y; part[14] += xv3 * wv.z; part[15] += xv3 * wv.w;
    }
#pragma unroll
    for (int i = 0; i < 16; ++i) acc[i] += part[i];
  }
  __syncthreads();

#pragma unroll
  for (int i = 0; i < 4; ++i) {
    int t = t0 + i;
    float tie = (float)((double)t * (1e-6 / 31.0));
#pragma unroll
    for (int j = 0; j < 4; ++j) {
      int es = es0 + j;
      lg[t * NES + es] = (acc[i * 4 + j] + bc[es]) + tie;
    }
  }
  __syncthreads();
  if (tid < NES) {
    float m = -INFINITY;
    for (int t = 0; t < GT; ++t) m = fmaxf(m, lg[t * NES + tid]);
    unsigned int msk = 0u;
    for (int t = 0; t < GT; ++t) if (lg[t * NES + tid] == m) msk |= (1u << t);
    sel[(size_t)g * NES + tid] = msk;
  }
}

// ---------------------------------------------------------------------------
// kW2: repack W2 f32 [es][d][f] -> bf16 MFMA-B fragment order (verified r2).
// ---------------------------------------------------------------------------
__global__ __launch_bounds__(256) void kW2(const float* __restrict__ W2,
                                           unsigned short* __restrict__ W2f) {
  int idx = blockIdx.x * 256 + threadIdx.x;      // (es, dt, lane)
  int l = idx & 63, dt = (idx >> 6) & 63, es = idx >> 12;
  const float* src = W2 + ((size_t)es * DM + dt * 16 + (l & 15)) * FSZ + (l >> 4) * 8;
  float4 a = *(const float4*)src;
  float4 b = *(const float4*)(src + 4);
  s16x8 v;
  v[0] = (short)f2bf(a.x); v[1] = (short)f2bf(a.y);
  v[2] = (short)f2bf(a.z); v[3] = (short)f2bf(a.w);
  v[4] = (short)f2bf(b.x); v[5] = (short)f2bf(b.y);
  v[6] = (short)f2bf(b.z); v[7] = (short)f2bf(b.w);
  *(s16x8*)(W2f + (size_t)idx * 8) = v;
}

// ---------------------------------------------------------------------------
// Kernel B: inner = relu(xsel . W1[es] + b1[es]) -> bf16, layout [es][g][f].
// ---------------------------------------------------------------------------
__global__ __launch_bounds__(256, 2) void kB(const float* __restrict__ x,
                                             const float* __restrict__ W1,
                                             const float* __restrict__ b1,
                                             const unsigned int* __restrict__ sel,
                                             unsigned short* __restrict__ innerb) {
  __shared__ float w1s[256 * FSZ];
  __shared__ float xss[32 * 256];
  __shared__ unsigned int msks[32];
  const int bid = blockIdx.x;
  const int es  = bid >> 4;
  const int g0  = (bid & 15) * 32;
  const int tid = threadIdx.x;
  const int f   = tid & 31;
  const int gp  = tid >> 5;
  if (tid < 32) msks[tid] = sel[(size_t)(g0 + tid) * NES + es];

  float acc[4] = {0.f, 0.f, 0.f, 0.f};
  for (int c = 0; c < 4; ++c) {
    const int d0 = c * 256;
    __syncthreads();
    const float* w1p = W1 + (size_t)es * DM * FSZ + (size_t)d0 * FSZ;
#pragma unroll
    for (int k = 0; k < 8; ++k) {
      int idx = (tid + 256 * k) * 4;
      *(float4*)&w1s[idx] = *(const float4*)&w1p[idx];
    }
    {
      int r = tid >> 3, p = tid & 7;
      unsigned int m = msks[r];
      size_t grow = (size_t)(g0 + r) * GT;
      if (m & (m - 1)) {                    // rare multi-tie: dispatch the SUM
        for (int j = 0; j < 32; ++j) {
          float v = 0.f; unsigned int mm = m;
          while (mm) { int tt = __ffs(mm) - 1; mm &= mm - 1;
            v += x[(grow + tt) * DM + d0 + p * 32 + j]; }
          xss[r * 256 + p * 32 + j] = v;
        }
      } else {
        int t = __ffs(m) - 1;
        const float4* xr = (const float4*)(x + (grow + t) * DM + d0 + p * 32);
        float4* dst = (float4*)&xss[r * 256 + p * 32];
#pragma unroll
        for (int j = 0; j < 8; ++j) dst[j] = xr[j];
      }
    }
    __syncthreads();
    for (int dd = 0; dd < 256; dd += 4) {
      float wv0 = w1s[(dd + 0) * FSZ + f];
      float wv1 = w1s[(dd + 1) * FSZ + f];
      float wv2 = w1s[(dd + 2) * FSZ + f];
      float wv3 = w1s[(dd + 3) * FSZ + f];
#pragma unroll
      for (int i = 0; i < 4; ++i) {
        float4 xv = *(const float4*)&xss[(gp + i * 8) * 256 + dd];
        acc[i] += fmaf(xv.x, wv0, fmaf(xv.y, wv1, fmaf(xv.z, wv2, xv.w * wv3)));
      }
    }
  }
  float b1v = b1[es * FSZ + f];
#pragma unroll
  for (int i = 0; i < 4; ++i) {
    int g = g0 + gp + i * 8;
    innerb[((size_t)es * NGRP + g) * FSZ + f] = f2bf(fmaxf(acc[i] + b1v, 0.f));
  }
}

// ---------------------------------------------------------------------------
// kC1: per-es dense GEMM (512g x 32f).(32f x 1024d) -> Rb bf16 [g][Ec][d],
// b2 folded. 4 waves x (64g x 64d), 16 mfma each, no LDS, no barriers.
// ---------------------------------------------------------------------------
__global__ __launch_bounds__(256) void kC1(const unsigned short* __restrict__ innerb,
                                           const unsigned short* __restrict__ W2f,
                                           const float* __restrict__ b2,
                                           unsigned short* __restrict__ Rb,
                                           int es0, int Ec) {
  const int bid = blockIdx.x;
  const int esl = bid >> 5;             // chunk-local es
  const int es  = es0 + esl;
  const int mt  = (bid >> 3) & 3;       // 128-g tile
  const int nt  = bid & 7;              // 128-d tile
  const int tid = threadIdx.x;
  const int l = tid & 63, w = tid >> 6;
  const int r15 = l & 15, q = l >> 4;
  const int g0 = mt * 128 + (w >> 1) * 64;
  const int n0 = nt * 128 + (w & 1) * 64;

  const unsigned short* Ab = innerb + ((size_t)es * NGRP + g0 + r15) * FSZ + q * 8;
  const unsigned short* Bb = W2f + (((size_t)es * 64 + (n0 >> 4)) * 64 + l) * 8;
  s16x8 a[4], b[4];
#pragma unroll
  for (int i = 0; i < 4; ++i) a[i] = *(const s16x8*)(Ab + (size_t)i * 16 * FSZ);
#pragma unroll
  for (int j = 0; j < 4; ++j) b[j] = *(const s16x8*)(Bb + (size_t)j * 64 * 8);

  const f32x4 z = {0.f, 0.f, 0.f, 0.f};
  f32x4 acc[4][4];
#pragma unroll
  for (int i = 0; i < 4; ++i)
#pragma unroll
    for (int j = 0; j < 4; ++j)
      acc[i][j] = __builtin_amdgcn_mfma_f32_16x16x32_bf16(a[i], b[j], z, 0, 0, 0);

#pragma unroll
  for (int j = 0; j < 4; ++j) {
    const int col = n0 + j * 16 + r15;
    const float b2v = b2[(size_t)es * DM + col];
#pragma unroll
    for (int i = 0; i < 4; ++i) {
#pragma unroll
      for (int r = 0; r < 4; ++r) {
        const int g = g0 + i * 16 + q * 4 + r;    // C/D: row=(lane>>4)*4+reg
        Rb[((size_t)g * Ec + esl) * DM + col] = f2bf(acc[i][j][r] + b2v);
      }
    }
  }
}

// ---------------------------------------------------------------------------
// kC2: per-group gather-combine. Invert sel to per-token es-lists in LDS,
// then each (t, d-part) thread sums its rows (bf16->f32) and += into out.
// ---------------------------------------------------------------------------
__global__ __launch_bounds__(256) void kC2(const unsigned short* __restrict__ Rb,
                                           const unsigned int* __restrict__ sel,
                                           float* __restrict__ out,
                                           int es0, int Ec) {
  __shared__ unsigned int cnt[32];
  __shared__ unsigned char list[32][128];
  const int g = blockIdx.x;
  const int tid = threadIdx.x;
  if (tid < 32) cnt[tid] = 0;
  __syncthreads();
  if (tid < Ec) {
    unsigned int m = sel[(size_t)g * NES + es0 + tid];
    while (m) { int t = __ffs(m) - 1; m &= m - 1;
      unsigned int p = atomicAdd(&cnt[t], 1u);
      list[t][p] = (unsigned char)tid; }
  }
  __syncthreads();
  const int t = tid >> 3, part = tid & 7;
  const int n = (int)cnt[t];
#pragma unroll
  for (int h = 0; h < 2; ++h) {
    const int d0 = part * 128 + h * 64;
    float acc[64];
#pragma unroll
    for (int i = 0; i < 64; ++i) acc[i] = 0.f;
    for (int e = 0; e < n; ++e) {
      const unsigned short* row = Rb + ((size_t)g * Ec + list[t][e]) * DM + d0;
#pragma unroll
      for (int v = 0; v < 8; ++v) {
        s16x8 rv = *(const s16x8*)(row + v * 8);
#pragma unroll
        for (int k = 0; k < 8; ++k) {
          union { unsigned int u; float f; } cv;
          cv.u = ((unsigned int)(unsigned short)rv[k]) << 16;
          acc[v * 8 + k] += cv.f;
        }
      }
    }
    float* op = out + ((size_t)g * GT + t) * DM + d0;
#pragma unroll
    for (int v = 0; v < 16; ++v) {
      float4 o = *(float4*)&op[v * 4];
      o.x += acc[v * 4]; o.y += acc[v * 4 + 1];
      o.z += acc[v * 4 + 2]; o.w += acc[v * 4 + 3];
      *(float4*)&op[v * 4] = o;
    }
  }
}

extern "C" void kernel_launch(void* const* d_in, const int* in_sizes, int n_in,
                              void* d_out, int out_size, void* d_ws, size_t ws_size,
                              hipStream_t stream) {
  const float* x  = (const float*)d_in[0];
  const float* Wc = (const float*)d_in[1];
  const float* bc = (const float*)d_in[2];
  const float* W1 = (const float*)d_in[3];
  const float* b1 = (const float*)d_in[4];
  const float* W2 = (const float*)d_in[5];
  const float* b2 = (const float*)d_in[6];
  float* out = (float*)d_out;

  // ws: sel u32 @0 (256 KB); innerb bf16 [es][g][f] @1 MB (4 MB);
  //     W2f bf16 frag-order @6 MB (8.4 MB); Rb bf16 [g][Ec][d] @15 MB.
  unsigned int* sel = (unsigned int*)d_ws;
  unsigned short* innerb = (unsigned short*)((char*)d_ws + (1u << 20));
  unsigned short* W2f = (unsigned short*)((char*)d_ws + (6u << 20));
  unsigned short* Rb  = (unsigned short*)((char*)d_ws + (15u << 20));

  // Largest es-chunk Ec (divisor of 128) whose Rb fits the workspace.
  int Ec = 128;
  while (Ec > 1 && (15u << 20) + (size_t)NGRP * Ec * DM * 2 > ws_size) Ec >>= 1;
  const int NC = NES / Ec;

  hipMemsetAsync(d_out, 0, (size_t)out_size * sizeof(float), stream);
  kA<<<NGRP, 256, 0, stream>>>(x, Wc, bc, sel);
  kW2<<<2048, 256, 0, stream>>>(W2, W2f);
  kB<<<NES * 16, 256, 0, stream>>>(x, W1, b1, sel, innerb);
  for (int c = 0; c < NC; ++c) {
    kC1<<<Ec * 32, 256, 0, stream>>>(innerb, W2f, b2, Rb, c * Ec, Ec);
    kC2<<<NGRP, 256, 0, stream>>>(Rb, sel, out, c * Ec, Ec);
  }
}

// Round 4
// 278.486 us; speedup vs baseline: 2.1234x; 1.3789x over previous
//
#include <hip/hip_runtime.h>
#include <hip/hip_bf16.h>

// BatchSplitFF: DM=1024, NEXPERTS=32, SETS=4 (ES=128 pairs), ESIZE=32, B=2, S=8192
#define DM   1024
#define NES  128
#define GT   32
#define NGRP 512
#define FSZ  32

typedef float f32x4 __attribute__((ext_vector_type(4)));
typedef short s16x8 __attribute__((ext_vector_type(8)));

__device__ inline unsigned short f2bf(float f) {   // RNE f32->bf16
  union { float f; unsigned int u; } x; x.f = f;
  unsigned int r = x.u + 0x7fffu + ((x.u >> 16) & 1u);
  return (unsigned short)(r >> 16);
}
__device__ inline float bf2f(unsigned short h) {
  union { unsigned int u; float f; } x; x.u = ((unsigned int)h) << 16;
  return x.f;
}

// ---------------------------------------------------------------------------
// Kernel A: controller logits (f32, tree-accumulated) + argmax-equality mask.
// UNCHANGED (passed 3x; argmax is rounding-sensitive, stays f32).
// ---------------------------------------------------------------------------
__global__ __launch_bounds__(256, 2) void kA(const float* __restrict__ x,
                                             const float* __restrict__ Wc,
                                             const float* __restrict__ bc,
                                             unsigned int* __restrict__ sel) {
  __shared__ float wcs[64 * 128];
  __shared__ float xs[32 * 64];
  __shared__ float lg[32 * 128];
  const int g   = blockIdx.x;
  const int tid = threadIdx.x;
  const int es0 = (tid & 31) * 4;
  const int t0  = (tid >> 5) * 4;
  const float* xg = x + (size_t)g * GT * DM;

  float acc[16];
#pragma unroll
  for (int i = 0; i < 16; ++i) acc[i] = 0.f;

  for (int c = 0; c < 16; ++c) {
    const int d0 = c * 64;
    if (c) __syncthreads();
#pragma unroll
    for (int k = 0; k < 8; ++k) {
      int idx = (tid + 256 * k) * 4;
      int dd = idx >> 7, es = idx & 127;
      *(float4*)&wcs[idx] = *(const float4*)&Wc[(size_t)(d0 + dd) * NES + es];
    }
#pragma unroll
    for (int k = 0; k < 2; ++k) {
      int idx = (tid + 256 * k) * 4;
      int t = idx >> 6, dd = idx & 63;
      *(float4*)&xs[idx] = *(const float4*)&xg[(size_t)t * DM + d0 + dd];
    }
    __syncthreads();

    float part[16];
#pragma unroll
    for (int i = 0; i < 16; ++i) part[i] = 0.f;
    for (int dd = 0; dd < 64; ++dd) {
      float4 wv = *(const float4*)&wcs[dd * NES + es0];
      float xv0 = xs[(t0 + 0) * 64 + dd];
      float xv1 = xs[(t0 + 1) * 64 + dd];
      float xv2 = xs[(t0 + 2) * 64 + dd];
      float xv3 = xs[(t0 + 3) * 64 + dd];
      part[0]  += xv0 * wv.x; part[1]  += xv0 * wv.y; part[2]  += xv0 * wv.z; part[3]  += xv0 * wv.w;
      part[4]  += xv1 * wv.x; part[5]  += xv1 * wv.y; part[6]  += xv1 * wv.z; part[7]  += xv1 * wv.w;
      part[8]  += xv2 * wv.x; part[9]  += xv2 * wv.y; part[10] += xv2 * wv.z; part[11] += xv2 * wv.w;
      part[12] += xv3 * wv.x; part[13] += xv3 * wv.y; part[14] += xv3 * wv.z; part[15] += xv3 * wv.w;
    }
#pragma unroll
    for (int i = 0; i < 16; ++i) acc[i] += part[i];
  }
  __syncthreads();

#pragma unroll
  for (int i = 0; i < 4; ++i) {
    int t = t0 + i;
    float tie = (float)((double)t * (1e-6 / 31.0));
#pragma unroll
    for (int j = 0; j < 4; ++j) {
      int es = es0 + j;
      lg[t * NES + es] = (acc[i * 4 + j] + bc[es]) + tie;
    }
  }
  __syncthreads();
  if (tid < NES) {
    float m = -INFINITY;
    for (int t = 0; t < GT; ++t) m = fmaxf(m, lg[t * NES + tid]);
    unsigned int msk = 0u;
    for (int t = 0; t < GT; ++t) if (lg[t * NES + tid] == m) msk |= (1u << t);
    sel[(size_t)g * NES + tid] = msk;
  }
}

// ---------------------------------------------------------------------------
// kXB: x f32 -> bf16 (RNE), flat copy.
// ---------------------------------------------------------------------------
__global__ __launch_bounds__(256) void kXB(const float* __restrict__ x,
                                           unsigned short* __restrict__ xb) {
  size_t i = ((size_t)blockIdx.x * 256 + threadIdx.x) * 8;
  float4 a = *(const float4*)&x[i];
  float4 b = *(const float4*)&x[i + 4];
  s16x8 v;
  v[0] = (short)f2bf(a.x); v[1] = (short)f2bf(a.y);
  v[2] = (short)f2bf(a.z); v[3] = (short)f2bf(a.w);
  v[4] = (short)f2bf(b.x); v[5] = (short)f2bf(b.y);
  v[6] = (short)f2bf(b.z); v[7] = (short)f2bf(b.w);
  *(s16x8*)&xb[i] = v;
}

// ---------------------------------------------------------------------------
// kW2: repack W2 f32 [es][d][f] -> bf16 MFMA-B frag order, K=f / N=d
// (for kC1: B[k=(l>>4)*8+i][col=l&15] = W2[es][dt*16+(l&15)][(l>>4)*8+i]).
// ---------------------------------------------------------------------------
__global__ __launch_bounds__(256) void kW2(const float* __restrict__ W2,
                                           unsigned short* __restrict__ W2f) {
  int idx = blockIdx.x * 256 + threadIdx.x;      // (es, dt, lane)
  int l = idx & 63, dt = (idx >> 6) & 63, es = idx >> 12;
  const float* src = W2 + ((size_t)es * DM + dt * 16 + (l & 15)) * FSZ + (l >> 4) * 8;
  float4 a = *(const float4*)src;
  float4 b = *(const float4*)(src + 4);
  s16x8 v;
  v[0] = (short)f2bf(a.x); v[1] = (short)f2bf(a.y);
  v[2] = (short)f2bf(a.z); v[3] = (short)f2bf(a.w);
  v[4] = (short)f2bf(b.x); v[5] = (short)f2bf(b.y);
  v[6] = (short)f2bf(b.z); v[7] = (short)f2bf(b.w);
  *(s16x8*)(W2f + (size_t)idx * 8) = v;
}

// ---------------------------------------------------------------------------
// kW1: repack W1 f32 [es][d][f] -> bf16 MFMA-B frag order, K=d / N=f
// (for kBm: B[k][n] = W1[es][kt*32 + (l>>4)*8+i][nh*16 + (l&15)]).
// Layout: W1f[((es*32 + kt)*2 + nh)*64 + l][i]
// ---------------------------------------------------------------------------
__global__ __launch_bounds__(256) void kW1(const float* __restrict__ W1,
                                           unsigned short* __restrict__ W1f) {
  int idx = blockIdx.x * 256 + threadIdx.x;      // (es, kt, nh, lane)
  int l = idx & 63, nh = (idx >> 6) & 1, kt = (idx >> 7) & 31, es = idx >> 12;
  const float* src = W1 + ((size_t)es * DM + kt * 32 + (l >> 4) * 8) * FSZ
                        + nh * 16 + (l & 15);
  s16x8 v;
#pragma unroll
  for (int i = 0; i < 8; ++i) v[i] = (short)f2bf(src[(size_t)i * FSZ]);
  *(s16x8*)(W1f + (size_t)idx * 8) = v;
}

// ---------------------------------------------------------------------------
// kBm: inner = relu(xsel . W1[es] + b1[es]) via MFMA. Block = (es, 128-group
// quarter); 4 waves x (32g x 32f x K=1024). Gathered A-rows staged per
// K-chunk(128) in XOR-swizzled LDS; B-frags straight from L2-resident W1f.
// ---------------------------------------------------------------------------
__global__ __launch_bounds__(256, 2) void kBm(const unsigned short* __restrict__ xb,
                                              const unsigned short* __restrict__ W1f,
                                              const float* __restrict__ b1,
                                              const unsigned int* __restrict__ sel,
                                              unsigned short* __restrict__ innerb) {
  __shared__ unsigned short As[128 * 128];   // [row][k] bf16, byte^((row&7)<<4)
  __shared__ int tokL[128];
  __shared__ unsigned int mulL[128];
  const int bid = blockIdx.x;
  const int es = bid >> 2, g0 = (bid & 3) * 128;
  const int tid = threadIdx.x;
  const int l = tid & 63, w = tid >> 6;
  const int r15 = l & 15, q = l >> 4;
  const int mw = w * 32;

  if (tid < 128) {
    unsigned int m = sel[(size_t)(g0 + tid) * NES + es];
    tokL[tid] = (g0 + tid) * GT + (__ffs(m) - 1);
    mulL[tid] = (m & (m - 1)) ? m : 0u;
  }

  const int r = tid >> 1, p = tid & 1;       // gather role: row, k-half
  const int swz = (r & 7) << 4;
  const unsigned int dbase = (unsigned int)r * 256 + (unsigned int)p * 128;

  f32x4 acc[2][2];
#pragma unroll
  for (int i = 0; i < 2; ++i)
#pragma unroll
    for (int j = 0; j < 2; ++j) acc[i][j] = (f32x4){0.f, 0.f, 0.f, 0.f};

  for (int c = 0; c < 8; ++c) {
    __syncthreads();                          // consumers of prev chunk done
    unsigned int mm = mulL[r];
    if (!mm) {                                // common path: single token
      const unsigned short* src = xb + (size_t)tokL[r] * DM + c * 128 + p * 64;
#pragma unroll
      for (int j = 0; j < 8; ++j) {
        s16x8 v = *(const s16x8*)(src + j * 8);
        *(s16x8*)((char*)As + ((dbase + j * 16) ^ swz)) = v;
      }
    } else {                                  // rare ties: f32 row-sum
      size_t grow = (size_t)(g0 + r) * GT;
#pragma unroll
      for (int j = 0; j < 8; ++j) {
        float av[8] = {0.f, 0.f, 0.f, 0.f, 0.f, 0.f, 0.f, 0.f};
        unsigned int m2 = mm;
        while (m2) {
          int tt = __ffs(m2) - 1; m2 &= m2 - 1;
          s16x8 v = *(const s16x8*)(xb + (grow + tt) * DM + c * 128 + p * 64 + j * 8);
#pragma unroll
          for (int k = 0; k < 8; ++k) av[k] += bf2f((unsigned short)v[k]);
        }
        s16x8 o;
#pragma unroll
        for (int k = 0; k < 8; ++k) o[k] = (short)f2bf(av[k]);
        *(s16x8*)((char*)As + ((dbase + j * 16) ^ swz)) = o;
      }
    }
    __syncthreads();

#pragma unroll
    for (int s = 0; s < 4; ++s) {
      const int ks = c * 4 + s;
      const unsigned short* bp = W1f + ((size_t)es * 32 + ks) * 1024 + l * 8;
      s16x8 bf0 = *(const s16x8*)bp;
      s16x8 bf1 = *(const s16x8*)(bp + 512);
      const int row0 = mw + r15, row1 = mw + 16 + r15;
      s16x8 a0 = *(const s16x8*)((char*)As +
                   (((unsigned)row0 * 256 + s * 64 + q * 16) ^ ((row0 & 7) << 4)));
      s16x8 a1 = *(const s16x8*)((char*)As +
                   (((unsigned)row1 * 256 + s * 64 + q * 16) ^ ((row1 & 7) << 4)));
      acc[0][0] = __builtin_amdgcn_mfma_f32_16x16x32_bf16(a0, bf0, acc[0][0], 0, 0, 0);
      acc[0][1] = __builtin_amdgcn_mfma_f32_16x16x32_bf16(a0, bf1, acc[0][1], 0, 0, 0);
      acc[1][0] = __builtin_amdgcn_mfma_f32_16x16x32_bf16(a1, bf0, acc[1][0], 0, 0, 0);
      acc[1][1] = __builtin_amdgcn_mfma_f32_16x16x32_bf16(a1, bf1, acc[1][1], 0, 0, 0);
    }
  }

  float bia0 = b1[es * FSZ + r15];
  float bia1 = b1[es * FSZ + 16 + r15];
#pragma unroll
  for (int i = 0; i < 2; ++i)
#pragma unroll
    for (int rr = 0; rr < 4; ++rr) {
      int g = g0 + mw + i * 16 + q * 4 + rr;  // C/D: row=(lane>>4)*4+reg
      unsigned short* op = innerb + ((size_t)es * NGRP + g) * FSZ;
      op[r15]      = f2bf(fmaxf(acc[i][0][rr] + bia0, 0.f));
      op[16 + r15] = f2bf(fmaxf(acc[i][1][rr] + bia1, 0.f));
    }
}

// ---------------------------------------------------------------------------
// kC1: per-es dense GEMM (512g x 32f).(32f x 1024d) -> Rb bf16 [g][Ec][d],
// b2 folded. 4 waves x (64g x 64d), 16 mfma each, no LDS, no barriers.
// ---------------------------------------------------------------------------
__global__ __launch_bounds__(256) void kC1(const unsigned short* __restrict__ innerb,
                                           const unsigned short* __restrict__ W2f,
                                           const float* __restrict__ b2,
                                           unsigned short* __restrict__ Rb,
                                           int es0, int Ec) {
  const int bid = blockIdx.x;
  const int esl = bid >> 5;
  const int es  = es0 + esl;
  const int mt  = (bid >> 3) & 3;
  const int nt  = bid & 7;
  const int tid = threadIdx.x;
  const int l = tid & 63, w = tid >> 6;
  const int r15 = l & 15, q = l >> 4;
  const int g0 = mt * 128 + (w >> 1) * 64;
  const int n0 = nt * 128 + (w & 1) * 64;

  const unsigned short* Ab = innerb + ((size_t)es * NGRP + g0 + r15) * FSZ + q * 8;
  const unsigned short* Bb = W2f + (((size_t)es * 64 + (n0 >> 4)) * 64 + l) * 8;
  s16x8 a[4], b[4];
#pragma unroll
  for (int i = 0; i < 4; ++i) a[i] = *(const s16x8*)(Ab + (size_t)i * 16 * FSZ);
#pragma unroll
  for (int j = 0; j < 4; ++j) b[j] = *(const s16x8*)(Bb + (size_t)j * 64 * 8);

  const f32x4 z = {0.f, 0.f, 0.f, 0.f};
  f32x4 acc[4][4];
#pragma unroll
  for (int i = 0; i < 4; ++i)
#pragma unroll
    for (int j = 0; j < 4; ++j)
      acc[i][j] = __builtin_amdgcn_mfma_f32_16x16x32_bf16(a[i], b[j], z, 0, 0, 0);

#pragma unroll
  for (int j = 0; j < 4; ++j) {
    const int col = n0 + j * 16 + r15;
    const float b2v = b2[(size_t)es * DM + col];
#pragma unroll
    for (int i = 0; i < 4; ++i) {
#pragma unroll
      for (int r = 0; r < 4; ++r) {
        const int g = g0 + i * 16 + q * 4 + r;
        Rb[((size_t)g * Ec + esl) * DM + col] = f2bf(acc[i][j][r] + b2v);
      }
    }
  }
}

// ---------------------------------------------------------------------------
// kC2: per-group gather-combine. Invert sel to per-token es-lists in LDS,
// then each (t, d-part) thread sums its rows (bf16->f32) and += into out.
// ---------------------------------------------------------------------------
__global__ __launch_bounds__(256) void kC2(const unsigned short* __restrict__ Rb,
                                           const unsigned int* __restrict__ sel,
                                           float* __restrict__ out,
                                           int es0, int Ec) {
  __shared__ unsigned int cnt[32];
  __shared__ unsigned char list[32][128];
  const int g = blockIdx.x;
  const int tid = threadIdx.x;
  if (tid < 32) cnt[tid] = 0;
  __syncthreads();
  if (tid < Ec) {
    unsigned int m = sel[(size_t)g * NES + es0 + tid];
    while (m) { int t = __ffs(m) - 1; m &= m - 1;
      unsigned int p = atomicAdd(&cnt[t], 1u);
      list[t][p] = (unsigned char)tid; }
  }
  __syncthreads();
  const int t = tid >> 3, part = tid & 7;
  const int n = (int)cnt[t];
#pragma unroll
  for (int h = 0; h < 2; ++h) {
    const int d0 = part * 128 + h * 64;
    float acc[64];
#pragma unroll
    for (int i = 0; i < 64; ++i) acc[i] = 0.f;
    for (int e = 0; e < n; ++e) {
      const unsigned short* row = Rb + ((size_t)g * Ec + list[t][e]) * DM + d0;
#pragma unroll
      for (int v = 0; v < 8; ++v) {
        s16x8 rv = *(const s16x8*)(row + v * 8);
#pragma unroll
        for (int k = 0; k < 8; ++k) acc[v * 8 + k] += bf2f((unsigned short)rv[k]);
      }
    }
    float* op = out + ((size_t)g * GT + t) * DM + d0;
#pragma unroll
    for (int v = 0; v < 16; ++v) {
      float4 o = *(float4*)&op[v * 4];
      o.x += acc[v * 4]; o.y += acc[v * 4 + 1];
      o.z += acc[v * 4 + 2]; o.w += acc[v * 4 + 3];
      *(float4*)&op[v * 4] = o;
    }
  }
}

extern "C" void kernel_launch(void* const* d_in, const int* in_sizes, int n_in,
                              void* d_out, int out_size, void* d_ws, size_t ws_size,
                              hipStream_t stream) {
  const float* x  = (const float*)d_in[0];
  const float* Wc = (const float*)d_in[1];
  const float* bc = (const float*)d_in[2];
  const float* W1 = (const float*)d_in[3];
  const float* b1 = (const float*)d_in[4];
  const float* W2 = (const float*)d_in[5];
  const float* b2 = (const float*)d_in[6];
  float* out = (float*)d_out;

  // ws: sel @0 (256 KB); innerb @1M (4 MB); W2f @6M (8.4 MB);
  //     W1f @15M (8.4 MB, dead after kBm); xb @24M (33.5 MB, dead after kBm);
  //     Rb @15M overlapping W1f+xb (sequential stream => safe).
  unsigned int* sel = (unsigned int*)d_ws;
  unsigned short* innerb = (unsigned short*)((char*)d_ws + (1u << 20));
  unsigned short* W2f = (unsigned short*)((char*)d_ws + (6u << 20));
  unsigned short* W1f = (unsigned short*)((char*)d_ws + (15u << 20));
  unsigned short* xb  = (unsigned short*)((char*)d_ws + (24u << 20));
  unsigned short* Rb  = (unsigned short*)((char*)d_ws + (15u << 20));

  int Ec = 128;
  while (Ec > 1 && (15u << 20) + (size_t)NGRP * Ec * DM * 2 > ws_size) Ec >>= 1;
  const int NC = NES / Ec;

  hipMemsetAsync(d_out, 0, (size_t)out_size * sizeof(float), stream);
  kA<<<NGRP, 256, 0, stream>>>(x, Wc, bc, sel);
  kXB<<<8192, 256, 0, stream>>>(x, xb);
  kW2<<<2048, 256, 0, stream>>>(W2, W2f);
  kW1<<<2048, 256, 0, stream>>>(W1, W1f);
  kBm<<<NGRP, 256, 0, stream>>>(xb, W1f, b1, sel, innerb);
  for (int c = 0; c < NC; ++c) {
    kC1<<<Ec * 32, 256, 0, stream>>>(innerb, W2f, b2, Rb, c * Ec, Ec);
    kC2<<<NGRP, 256, 0, stream>>>(Rb, sel, out, c * Ec, Ec);
  }
}

// Round 5
// 211.444 us; speedup vs baseline: 2.7966x; 1.3171x over previous
//
#include <hip/hip_runtime.h>
#include <hip/hip_bf16.h>

// BatchSplitFF: DM=1024, NEXPERTS=32, SETS=4 (ES=128 pairs), ESIZE=32, B=2, S=8192
#define DM   1024
#define NES  128
#define GT   32
#define NGRP 512
#define FSZ  32

typedef float f32x4 __attribute__((ext_vector_type(4)));
typedef short s16x8 __attribute__((ext_vector_type(8)));

__device__ inline unsigned short f2bf(float f) {   // RNE f32->bf16
  union { float f; unsigned int u; } x; x.f = f;
  unsigned int r = x.u + 0x7fffu + ((x.u >> 16) & 1u);
  return (unsigned short)(r >> 16);
}
__device__ inline float bf2f(unsigned short h) {
  union { unsigned int u; float f; } x; x.u = ((unsigned int)h) << 16;
  return x.f;
}

// ---------------------------------------------------------------------------
// Kernel A: controller logits (f32) + argmax-equality mask + x->bf16 emission.
// Accumulation order is bit-identical to rounds 1-4 (dd-sequential fma per
// (t,es), 64-dd part[] tree): argmax behavior unchanged. Inner loop now
// dd-vectorized (8x b128 per 64 FMA; xs reads are 32-lane broadcasts).
// ---------------------------------------------------------------------------
__global__ __launch_bounds__(256, 2) void kA(const float* __restrict__ x,
                                             const float* __restrict__ Wc,
                                             const float* __restrict__ bc,
                                             unsigned int* __restrict__ sel,
                                             unsigned short* __restrict__ xb) {
  __shared__ float wcs[64 * 128];
  __shared__ float xs[32 * 64];
  __shared__ float lg[32 * 128];
  const int g   = blockIdx.x;
  const int tid = threadIdx.x;
  const int es0 = (tid & 31) * 4;
  const int t0  = (tid >> 5) * 4;
  const float* xg = x + (size_t)g * GT * DM;

  float acc[16];
#pragma unroll
  for (int i = 0; i < 16; ++i) acc[i] = 0.f;

  for (int c = 0; c < 16; ++c) {
    const int d0 = c * 64;
    if (c) __syncthreads();
#pragma unroll
    for (int k = 0; k < 8; ++k) {
      int idx = (tid + 256 * k) * 4;
      int dd = idx >> 7, es = idx & 127;
      *(float4*)&wcs[idx] = *(const float4*)&Wc[(size_t)(d0 + dd) * NES + es];
    }
#pragma unroll
    for (int k = 0; k < 2; ++k) {
      int idx = (tid + 256 * k) * 4;
      int t = idx >> 6, dd = idx & 63;
      *(float4*)&xs[idx] = *(const float4*)&xg[(size_t)t * DM + d0 + dd];
    }
    __syncthreads();

    {   // emit bf16 x chunk (fused former kXB): thread owns 8 staged elems
      int idx = tid * 8;
      int t = idx >> 6, col = idx & 63;
      float4 a = *(const float4*)&xs[idx];
      float4 b = *(const float4*)&xs[idx + 4];
      s16x8 v;
      v[0] = (short)f2bf(a.x); v[1] = (short)f2bf(a.y);
      v[2] = (short)f2bf(a.z); v[3] = (short)f2bf(a.w);
      v[4] = (short)f2bf(b.x); v[5] = (short)f2bf(b.y);
      v[6] = (short)f2bf(b.z); v[7] = (short)f2bf(b.w);
      *(s16x8*)&xb[((size_t)g * GT + t) * DM + d0 + col] = v;
    }

    float part[16];
#pragma unroll
    for (int i = 0; i < 16; ++i) part[i] = 0.f;
#pragma unroll 4
    for (int dd = 0; dd < 64; dd += 4) {
      float4 w0 = *(const float4*)&wcs[(dd + 0) * NES + es0];
      float4 w1 = *(const float4*)&wcs[(dd + 1) * NES + es0];
      float4 w2 = *(const float4*)&wcs[(dd + 2) * NES + es0];
      float4 w3 = *(const float4*)&wcs[(dd + 3) * NES + es0];
      float4 xv0 = *(const float4*)&xs[(t0 + 0) * 64 + dd];
      float4 xv1 = *(const float4*)&xs[(t0 + 1) * 64 + dd];
      float4 xv2 = *(const float4*)&xs[(t0 + 2) * 64 + dd];
      float4 xv3 = *(const float4*)&xs[(t0 + 3) * 64 + dd];
#define KSTEP(i, XV)                                                       \
      part[i*4+0] = fmaf(XV.x, w0.x, part[i*4+0]);                         \
      part[i*4+1] = fmaf(XV.x, w0.y, part[i*4+1]);                         \
      part[i*4+2] = fmaf(XV.x, w0.z, part[i*4+2]);                         \
      part[i*4+3] = fmaf(XV.x, w0.w, part[i*4+3]);                         \
      part[i*4+0] = fmaf(XV.y, w1.x, part[i*4+0]);                         \
      part[i*4+1] = fmaf(XV.y, w1.y, part[i*4+1]);                         \
      part[i*4+2] = fmaf(XV.y, w1.z, part[i*4+2]);                         \
      part[i*4+3] = fmaf(XV.y, w1.w, part[i*4+3]);                         \
      part[i*4+0] = fmaf(XV.z, w2.x, part[i*4+0]);                         \
      part[i*4+1] = fmaf(XV.z, w2.y, part[i*4+1]);                         \
      part[i*4+2] = fmaf(XV.z, w2.z, part[i*4+2]);                         \
      part[i*4+3] = fmaf(XV.z, w2.w, part[i*4+3]);                         \
      part[i*4+0] = fmaf(XV.w, w3.x, part[i*4+0]);                         \
      part[i*4+1] = fmaf(XV.w, w3.y, part[i*4+1]);                         \
      part[i*4+2] = fmaf(XV.w, w3.z, part[i*4+2]);                         \
      part[i*4+3] = fmaf(XV.w, w3.w, part[i*4+3]);
      KSTEP(0, xv0) KSTEP(1, xv1) KSTEP(2, xv2) KSTEP(3, xv3)
#undef KSTEP
    }
#pragma unroll
    for (int i = 0; i < 16; ++i) acc[i] += part[i];
  }
  __syncthreads();

#pragma unroll
  for (int i = 0; i < 4; ++i) {
    int t = t0 + i;
    float tie = (float)((double)t * (1e-6 / 31.0));
#pragma unroll
    for (int j = 0; j < 4; ++j) {
      int es = es0 + j;
      lg[t * NES + es] = (acc[i * 4 + j] + bc[es]) + tie;
    }
  }
  __syncthreads();
  if (tid < NES) {
    float m = -INFINITY;
    for (int t = 0; t < GT; ++t) m = fmaxf(m, lg[t * NES + tid]);
    unsigned int msk = 0u;
    for (int t = 0; t < GT; ++t) if (lg[t * NES + tid] == m) msk |= (1u << t);
    sel[(size_t)g * NES + tid] = msk;
  }
}

// ---------------------------------------------------------------------------
// kW2: repack W2 f32 [es][d][f] -> bf16 MFMA-B frag order, K=f / N=d.
// ---------------------------------------------------------------------------
__global__ __launch_bounds__(256) void kW2(const float* __restrict__ W2,
                                           unsigned short* __restrict__ W2f) {
  int idx = blockIdx.x * 256 + threadIdx.x;      // (es, dt, lane)
  int l = idx & 63, dt = (idx >> 6) & 63, es = idx >> 12;
  const float* src = W2 + ((size_t)es * DM + dt * 16 + (l & 15)) * FSZ + (l >> 4) * 8;
  float4 a = *(const float4*)src;
  float4 b = *(const float4*)(src + 4);
  s16x8 v;
  v[0] = (short)f2bf(a.x); v[1] = (short)f2bf(a.y);
  v[2] = (short)f2bf(a.z); v[3] = (short)f2bf(a.w);
  v[4] = (short)f2bf(b.x); v[5] = (short)f2bf(b.y);
  v[6] = (short)f2bf(b.z); v[7] = (short)f2bf(b.w);
  *(s16x8*)(W2f + (size_t)idx * 8) = v;
}

// ---------------------------------------------------------------------------
// kW1: repack W1 f32 [es][d][f] -> bf16 MFMA-B frag order, K=d / N=f.
// ---------------------------------------------------------------------------
__global__ __launch_bounds__(256) void kW1(const float* __restrict__ W1,
                                           unsigned short* __restrict__ W1f) {
  int idx = blockIdx.x * 256 + threadIdx.x;      // (es, kt, nh, lane)
  int l = idx & 63, nh = (idx >> 6) & 1, kt = (idx >> 7) & 31, es = idx >> 12;
  const float* src = W1 + ((size_t)es * DM + kt * 32 + (l >> 4) * 8) * FSZ
                        + nh * 16 + (l & 15);
  s16x8 v;
#pragma unroll
  for (int i = 0; i < 8; ++i) v[i] = (short)f2bf(src[(size_t)i * FSZ]);
  *(s16x8*)(W1f + (size_t)idx * 8) = v;
}

// ---------------------------------------------------------------------------
// kBm: inner = relu(xsel . W1[es] + b1[es]) via MFMA (unchanged from r4).
// ---------------------------------------------------------------------------
__global__ __launch_bounds__(256, 2) void kBm(const unsigned short* __restrict__ xb,
                                              const unsigned short* __restrict__ W1f,
                                              const float* __restrict__ b1,
                                              const unsigned int* __restrict__ sel,
                                              unsigned short* __restrict__ innerb) {
  __shared__ unsigned short As[128 * 128];   // [row][k] bf16, byte^((row&7)<<4)
  __shared__ int tokL[128];
  __shared__ unsigned int mulL[128];
  const int bid = blockIdx.x;
  const int es = bid >> 2, g0 = (bid & 3) * 128;
  const int tid = threadIdx.x;
  const int l = tid & 63, w = tid >> 6;
  const int r15 = l & 15, q = l >> 4;
  const int mw = w * 32;

  if (tid < 128) {
    unsigned int m = sel[(size_t)(g0 + tid) * NES + es];
    tokL[tid] = (g0 + tid) * GT + (__ffs(m) - 1);
    mulL[tid] = (m & (m - 1)) ? m : 0u;
  }

  const int r = tid >> 1, p = tid & 1;
  const int swz = (r & 7) << 4;
  const unsigned int dbase = (unsigned int)r * 256 + (unsigned int)p * 128;

  f32x4 acc[2][2];
#pragma unroll
  for (int i = 0; i < 2; ++i)
#pragma unroll
    for (int j = 0; j < 2; ++j) acc[i][j] = (f32x4){0.f, 0.f, 0.f, 0.f};

  for (int c = 0; c < 8; ++c) {
    __syncthreads();
    unsigned int mm = mulL[r];
    if (!mm) {
      const unsigned short* src = xb + (size_t)tokL[r] * DM + c * 128 + p * 64;
#pragma unroll
      for (int j = 0; j < 8; ++j) {
        s16x8 v = *(const s16x8*)(src + j * 8);
        *(s16x8*)((char*)As + ((dbase + j * 16) ^ swz)) = v;
      }
    } else {
      size_t grow = (size_t)(g0 + r) * GT;
#pragma unroll
      for (int j = 0; j < 8; ++j) {
        float av[8] = {0.f, 0.f, 0.f, 0.f, 0.f, 0.f, 0.f, 0.f};
        unsigned int m2 = mm;
        while (m2) {
          int tt = __ffs(m2) - 1; m2 &= m2 - 1;
          s16x8 v = *(const s16x8*)(xb + (grow + tt) * DM + c * 128 + p * 64 + j * 8);
#pragma unroll
          for (int k = 0; k < 8; ++k) av[k] += bf2f((unsigned short)v[k]);
        }
        s16x8 o;
#pragma unroll
        for (int k = 0; k < 8; ++k) o[k] = (short)f2bf(av[k]);
        *(s16x8*)((char*)As + ((dbase + j * 16) ^ swz)) = o;
      }
    }
    __syncthreads();

#pragma unroll
    for (int s = 0; s < 4; ++s) {
      const int ks = c * 4 + s;
      const unsigned short* bp = W1f + ((size_t)es * 32 + ks) * 1024 + l * 8;
      s16x8 bf0 = *(const s16x8*)bp;
      s16x8 bf1 = *(const s16x8*)(bp + 512);
      const int row0 = mw + r15, row1 = mw + 16 + r15;
      s16x8 a0 = *(const s16x8*)((char*)As +
                   (((unsigned)row0 * 256 + s * 64 + q * 16) ^ ((row0 & 7) << 4)));
      s16x8 a1 = *(const s16x8*)((char*)As +
                   (((unsigned)row1 * 256 + s * 64 + q * 16) ^ ((row1 & 7) << 4)));
      acc[0][0] = __builtin_amdgcn_mfma_f32_16x16x32_bf16(a0, bf0, acc[0][0], 0, 0, 0);
      acc[0][1] = __builtin_amdgcn_mfma_f32_16x16x32_bf16(a0, bf1, acc[0][1], 0, 0, 0);
      acc[1][0] = __builtin_amdgcn_mfma_f32_16x16x32_bf16(a1, bf0, acc[1][0], 0, 0, 0);
      acc[1][1] = __builtin_amdgcn_mfma_f32_16x16x32_bf16(a1, bf1, acc[1][1], 0, 0, 0);
    }
  }

  float bia0 = b1[es * FSZ + r15];
  float bia1 = b1[es * FSZ + 16 + r15];
#pragma unroll
  for (int i = 0; i < 2; ++i)
#pragma unroll
    for (int rr = 0; rr < 4; ++rr) {
      int g = g0 + mw + i * 16 + q * 4 + rr;
      unsigned short* op = innerb + ((size_t)es * NGRP + g) * FSZ;
      op[r15]      = f2bf(fmaxf(acc[i][0][rr] + bia0, 0.f));
      op[16 + r15] = f2bf(fmaxf(acc[i][1][rr] + bia1, 0.f));
    }
}

// ---------------------------------------------------------------------------
// kC1: per-es dense GEMM (512g x 32f).(32f x 1024d) -> Rb bf16 [g][Ec][d],
// b2 folded (unchanged from r4).
// ---------------------------------------------------------------------------
__global__ __launch_bounds__(256) void kC1(const unsigned short* __restrict__ innerb,
                                           const unsigned short* __restrict__ W2f,
                                           const float* __restrict__ b2,
                                           unsigned short* __restrict__ Rb,
                                           int es0, int Ec) {
  const int bid = blockIdx.x;
  const int esl = bid >> 5;
  const int es  = es0 + esl;
  const int mt  = (bid >> 3) & 3;
  const int nt  = bid & 7;
  const int tid = threadIdx.x;
  const int l = tid & 63, w = tid >> 6;
  const int r15 = l & 15, q = l >> 4;
  const int g0 = mt * 128 + (w >> 1) * 64;
  const int n0 = nt * 128 + (w & 1) * 64;

  const unsigned short* Ab = innerb + ((size_t)es * NGRP + g0 + r15) * FSZ + q * 8;
  const unsigned short* Bb = W2f + (((size_t)es * 64 + (n0 >> 4)) * 64 + l) * 8;
  s16x8 a[4], b[4];
#pragma unroll
  for (int i = 0; i < 4; ++i) a[i] = *(const s16x8*)(Ab + (size_t)i * 16 * FSZ);
#pragma unroll
  for (int j = 0; j < 4; ++j) b[j] = *(const s16x8*)(Bb + (size_t)j * 64 * 8);

  const f32x4 z = {0.f, 0.f, 0.f, 0.f};
  f32x4 acc[4][4];
#pragma unroll
  for (int i = 0; i < 4; ++i)
#pragma unroll
    for (int j = 0; j < 4; ++j)
      acc[i][j] = __builtin_amdgcn_mfma_f32_16x16x32_bf16(a[i], b[j], z, 0, 0, 0);

#pragma unroll
  for (int j = 0; j < 4; ++j) {
    const int col = n0 + j * 16 + r15;
    const float b2v = b2[(size_t)es * DM + col];
#pragma unroll
    for (int i = 0; i < 4; ++i) {
#pragma unroll
      for (int r = 0; r < 4; ++r) {
        const int g = g0 + i * 16 + q * 4 + r;
        Rb[((size_t)g * Ec + esl) * DM + col] = f2bf(acc[i][j][r] + b2v);
      }
    }
  }
}

// ---------------------------------------------------------------------------
// kC2: per-(group, d-quarter) gather-combine. 2048 blocks (4x r4 concurrency),
// 1-deep row prefetch, direct write when single-chunk (no out RMW, no memset).
// ---------------------------------------------------------------------------
__global__ __launch_bounds__(256) void kC2(const unsigned short* __restrict__ Rb,
                                           const unsigned int* __restrict__ sel,
                                           float* __restrict__ out,
                                           int es0, int Ec, int direct) {
  __shared__ unsigned int cnt[32];
  __shared__ unsigned char list[32][128];
  const int bid = blockIdx.x;
  const int g = bid >> 2, dq = bid & 3;
  const int tid = threadIdx.x;
  if (tid < 32) cnt[tid] = 0;
  __syncthreads();
  if (tid < Ec) {
    unsigned int m = sel[(size_t)g * NES + es0 + tid];
    while (m) { int t = __ffs(m) - 1; m &= m - 1;
      unsigned int p = atomicAdd(&cnt[t], 1u);
      list[t][p] = (unsigned char)tid; }
  }
  __syncthreads();
  const int t = tid >> 3, part = tid & 7;
  const int d0 = dq * 256 + part * 32;
  const int n = (int)cnt[t];
  const unsigned short* base = Rb + (size_t)g * Ec * DM + d0;

  float acc[32];
#pragma unroll
  for (int i = 0; i < 32; ++i) acc[i] = 0.f;

  s16x8 cur[4];
  if (n) {
    const unsigned short* r = base + (size_t)list[t][0] * DM;
#pragma unroll
    for (int v = 0; v < 4; ++v) cur[v] = *(const s16x8*)(r + v * 8);
  }
  for (int e = 0; e < n; ++e) {
    s16x8 nxt[4];
    const bool more = (e + 1 < n);
    if (more) {
      const unsigned short* r = base + (size_t)list[t][e + 1] * DM;
#pragma unroll
      for (int v = 0; v < 4; ++v) nxt[v] = *(const s16x8*)(r + v * 8);
    }
#pragma unroll
    for (int v = 0; v < 4; ++v)
#pragma unroll
      for (int k = 0; k < 8; ++k)
        acc[v * 8 + k] += bf2f((unsigned short)cur[v][k]);
    if (more) {
#pragma unroll
      for (int v = 0; v < 4; ++v) cur[v] = nxt[v];
    }
  }

  float* op = out + ((size_t)g * GT + t) * DM + d0;
  if (direct) {
#pragma unroll
    for (int v = 0; v < 8; ++v)
      *(float4*)&op[v * 4] =
          make_float4(acc[v * 4], acc[v * 4 + 1], acc[v * 4 + 2], acc[v * 4 + 3]);
  } else {
#pragma unroll
    for (int v = 0; v < 8; ++v) {
      float4 o = *(float4*)&op[v * 4];
      o.x += acc[v * 4]; o.y += acc[v * 4 + 1];
      o.z += acc[v * 4 + 2]; o.w += acc[v * 4 + 3];
      *(float4*)&op[v * 4] = o;
    }
  }
}

extern "C" void kernel_launch(void* const* d_in, const int* in_sizes, int n_in,
                              void* d_out, int out_size, void* d_ws, size_t ws_size,
                              hipStream_t stream) {
  const float* x  = (const float*)d_in[0];
  const float* Wc = (const float*)d_in[1];
  const float* bc = (const float*)d_in[2];
  const float* W1 = (const float*)d_in[3];
  const float* b1 = (const float*)d_in[4];
  const float* W2 = (const float*)d_in[5];
  const float* b2 = (const float*)d_in[6];
  float* out = (float*)d_out;

  // ws: sel @0 (256 KB); innerb @1M (4 MB); W2f @6M (8.4 MB);
  //     W1f @15M (8.4 MB, dead after kBm); xb @24M (33.5 MB, dead after kBm);
  //     Rb @15M overlapping W1f+xb (sequential stream => safe).
  unsigned int* sel = (unsigned int*)d_ws;
  unsigned short* innerb = (unsigned short*)((char*)d_ws + (1u << 20));
  unsigned short* W2f = (unsigned short*)((char*)d_ws + (6u << 20));
  unsigned short* W1f = (unsigned short*)((char*)d_ws + (15u << 20));
  unsigned short* xb  = (unsigned short*)((char*)d_ws + (24u << 20));
  unsigned short* Rb  = (unsigned short*)((char*)d_ws + (15u << 20));

  int Ec = 128;
  while (Ec > 1 && (15u << 20) + (size_t)NGRP * Ec * DM * 2 > ws_size) Ec >>= 1;
  const int NC = NES / Ec;

  if (NC > 1)   // accumulate path needs zeroed out; single-chunk writes direct
    hipMemsetAsync(d_out, 0, (size_t)out_size * sizeof(float), stream);
  kA<<<NGRP, 256, 0, stream>>>(x, Wc, bc, sel, xb);
  kW2<<<2048, 256, 0, stream>>>(W2, W2f);
  kW1<<<2048, 256, 0, stream>>>(W1, W1f);
  kBm<<<NGRP, 256, 0, stream>>>(xb, W1f, b1, sel, innerb);
  for (int c = 0; c < NC; ++c) {
    kC1<<<Ec * 32, 256, 0, stream>>>(innerb, W2f, b2, Rb, c * Ec, Ec);
    kC2<<<NGRP * 4, 256, 0, stream>>>(Rb, sel, out, c * Ec, Ec, NC == 1);
  }
}